// Round 7
// baseline (358.551 us; speedup 1.0000x reference)
//
#include <hip/hip_runtime.h>
#include <stdint.h>

typedef unsigned short ushort_t;
typedef unsigned int uint32;

typedef __attribute__((ext_vector_type(8))) short short8;
typedef __attribute__((ext_vector_type(4))) float floatx4;

#define NEG_SLOPE 0.2f

__device__ __forceinline__ ushort_t f2bf(float f) {
    union { float f; uint32 u; } v; v.f = f;
    uint32 u = v.u;
    uint32 r = (u + 0x7fffu + ((u >> 16) & 1u)) >> 16;
    return (ushort_t)r;
}
__device__ __forceinline__ float2 bf2x(uint32 u) {
    union { uint32 u; float f; } a, b;
    a.u = u << 16; b.u = u & 0xffff0000u;
    float2 r; r.x = a.f; r.y = b.f; return r;
}

// ---------------- dtype sniffer ----------------
__global__ void k_sniff(const uint32* __restrict__ x, int* __restrict__ flag) {
    __shared__ int sh[256];
    int t = threadIdx.x;
    int c = 0;
    for (int i = t; i < 1024; i += 256) {
        uint32 h = x[i] & 0xFFFFu;
        uint32 e = (h >> 7) & 0xFFu;
        if (h == 0u || (e >= 100u && e <= 140u)) c++;
    }
    sh[t] = c; __syncthreads();
    for (int off = 128; off >= 1; off >>= 1) {
        if (t < off) sh[t] += sh[t + off];
        __syncthreads();
    }
    if (t == 0) flag[0] = (sh[0] >= 512) ? 1 : 0;
}

// ---------------- GEMM body ----------------
__device__ __forceinline__ void gemm_body(int bid, int tid,
                                          const void* __restrict__ actv,
                                          const ushort_t* __restrict__ W,
                                          ushort_t* __restrict__ hb,
                                          float* __restrict__ als,
                                          float* __restrict__ ald,
                                          const ushort_t* __restrict__ asrcp,
                                          const ushort_t* __restrict__ adstp,
                                          int N, int layer0,
                                          const int* __restrict__ flag) {
    int wid = tid >> 6, lane = tid & 63;
    int n0 = (bid * 4 + wid) * 16;
    int mrow = lane & 15, quad = lane >> 4;
    int n = n0 + mrow;
    bool isf32 = (layer0 && !flag[0]);
    short8 a[4];
    if (n < N) {
        if (isf32) {
            const float* ar = (const float*)actv + (size_t)n * 128 + quad * 8;
            #pragma unroll
            for (int kt = 0; kt < 4; kt++) {
                float4 fa = *(const float4*)(ar + kt * 32);
                float4 fb = *(const float4*)(ar + kt * 32 + 4);
                short8 v;
                v[0] = (short)f2bf(fa.x); v[1] = (short)f2bf(fa.y);
                v[2] = (short)f2bf(fa.z); v[3] = (short)f2bf(fa.w);
                v[4] = (short)f2bf(fb.x); v[5] = (short)f2bf(fb.y);
                v[6] = (short)f2bf(fb.z); v[7] = (short)f2bf(fb.w);
                a[kt] = v;
            }
        } else {
            const ushort_t* ar = (const ushort_t*)actv + (size_t)n * 128 + quad * 8;
            #pragma unroll
            for (int kt = 0; kt < 4; kt++) a[kt] = *(const short8*)(ar + kt * 32);
        }
    } else {
        #pragma unroll
        for (int kt = 0; kt < 4; kt++) { short8 z = {0,0,0,0,0,0,0,0}; a[kt] = z; }
    }
    float ps[4], pd[4];
    #pragma unroll
    for (int t = 0; t < 8; t++) {
        if ((t & 1) == 0) {
            #pragma unroll
            for (int r = 0; r < 4; r++) { ps[r] = 0.f; pd[r] = 0.f; }
        }
        const ushort_t* wr = W + (size_t)(t * 16 + mrow) * 128 + quad * 8;
        floatx4 acc = {0.f, 0.f, 0.f, 0.f};
        #pragma unroll
        for (int kt = 0; kt < 4; kt++) {
            short8 b = *(const short8*)(wr + kt * 32);
            acc = __builtin_amdgcn_mfma_f32_16x16x32_bf16(a[kt], b, acc, 0, 0, 0);
        }
        int col = t * 16 + mrow;
        union { uint32 u; float f; } cs, cd;
        cs.u = ((uint32)asrcp[col]) << 16;
        cd.u = ((uint32)adstp[col]) << 16;
        #pragma unroll
        for (int r = 0; r < 4; r++) {
            int rn = n0 + quad * 4 + r;
            if (rn < N) hb[(size_t)rn * 128 + col] = f2bf(acc[r]);
            ps[r] += acc[r] * cs.f;
            pd[r] += acc[r] * cd.f;
        }
        if (t & 1) {
            #pragma unroll
            for (int off = 1; off <= 8; off <<= 1) {
                #pragma unroll
                for (int r = 0; r < 4; r++) {
                    ps[r] += __shfl_xor(ps[r], off);
                    pd[r] += __shfl_xor(pd[r], off);
                }
            }
            int h = t >> 1;
            if (mrow < 8) {
                int r = mrow & 3;
                float vs = r == 0 ? ps[0] : r == 1 ? ps[1] : r == 2 ? ps[2] : ps[3];
                float vd = r == 0 ? pd[0] : r == 1 ? pd[1] : r == 2 ? pd[2] : pd[3];
                int rn = n0 + quad * 4 + r;
                if (rn < N) {
                    float* dp = (mrow < 4) ? als : ald;
                    dp[(size_t)rn * 4 + h] = (mrow < 4) ? vs : vd;
                }
            }
        }
    }
}

__global__ __launch_bounds__(256) void k_gemm(const void* __restrict__ actv,
                                              const ushort_t* __restrict__ W,
                                              ushort_t* __restrict__ hb,
                                              float* __restrict__ als,
                                              float* __restrict__ ald,
                                              const ushort_t* __restrict__ asrcp,
                                              const ushort_t* __restrict__ adstp,
                                              int N, const int* __restrict__ flag) {
    gemm_body(blockIdx.x, threadIdx.x, actv, W, hb, als, ald, asrcp, adstp, N, 0, flag);
}

// ---------------- fused: param canonicalization (197 blocks) | hist x4-unrolled (rest) ----------------
__global__ void k_f1(const void* W0, const void* W1, const void* W2,
                     const void* s0, const void* s1, const void* s2,
                     const void* a0, const void* a1, const void* a2,
                     const void* b0, const void* b1, const void* b2,
                     ushort_t* __restrict__ pblk, const int* __restrict__ flag,
                     const int* __restrict__ dst, int* __restrict__ cnt,
                     int* __restrict__ rank, int E) {
    if (blockIdx.x < 197) {
        int i = blockIdx.x * 256 + threadIdx.x;
        if (i >= 50304) return;
        const void* src; int off;
        if (i < 49152) {
            int seg = i / 16384; off = i % 16384;
            src = seg == 0 ? W0 : seg == 1 ? W1 : W2;
        } else if (i < 49536) {
            int j = i - 49152; int seg = j / 128; off = j % 128;
            src = seg == 0 ? s0 : seg == 1 ? s1 : s2;
        } else if (i < 49920) {
            int j = i - 49536; int seg = j / 128; off = j % 128;
            src = seg == 0 ? a0 : seg == 1 ? a1 : a2;
        } else {
            int j = i - 49920; int seg = j / 128; off = j % 128;
            src = seg == 0 ? b0 : seg == 1 ? b1 : b2;
        }
        if (flag[0]) pblk[i] = ((const ushort_t*)src)[off];
        else         pblk[i] = f2bf(((const float*)src)[off]);
    } else {
        int e0 = ((blockIdx.x - 197) * 256 + threadIdx.x) * 4;
        if (e0 + 3 < E) {
            int4 d4 = *(const int4*)(dst + e0);
            int r0 = atomicAdd(&cnt[d4.x], 1);
            int r1 = atomicAdd(&cnt[d4.y], 1);
            int r2 = atomicAdd(&cnt[d4.z], 1);
            int r3 = atomicAdd(&cnt[d4.w], 1);
            int4 r4 = {r0, r1, r2, r3};
            *(int4*)(rank + e0) = r4;
        } else {
            for (int e = e0; e < E; e++) rank[e] = atomicAdd(&cnt[dst[e]], 1);
        }
    }
}

// ---------------- scan_a (standalone, tiny) ----------------
__global__ void k_scan_a(const int* __restrict__ cnt, int* __restrict__ ro,
                         int* __restrict__ bsum, int n) {
    __shared__ int sd[256];
    int t = threadIdx.x;
    int base = blockIdx.x * 1024 + t * 4;
    int v0 = (base + 0 < n) ? cnt[base + 0] : 0;
    int v1 = (base + 1 < n) ? cnt[base + 1] : 0;
    int v2 = (base + 2 < n) ? cnt[base + 2] : 0;
    int v3 = (base + 3 < n) ? cnt[base + 3] : 0;
    int s = v0 + v1 + v2 + v3;
    sd[t] = s; __syncthreads();
    for (int off = 1; off < 256; off <<= 1) {
        int x = 0;
        if (t >= off) x = sd[t - off];
        __syncthreads();
        sd[t] += x;
        __syncthreads();
    }
    int run = sd[t] - s;
    run += v0; if (base + 0 < n) ro[base + 1] = run;
    run += v1; if (base + 1 < n) ro[base + 2] = run;
    run += v2; if (base + 2 < n) ro[base + 3] = run;
    run += v3; if (base + 3 < n) ro[base + 4] = run;
    if (t == 255) bsum[blockIdx.x] = sd[255];
}

__global__ void k_scan_bc(int* __restrict__ ro, const int* __restrict__ bsum,
                          int n, int nb) {
    __shared__ int pre[256];
    int t = threadIdx.x;
    if (t == 0) {
        int acc = 0;
        for (int b = 0; b < nb; b++) { pre[b] = acc; acc += bsum[b]; }
    }
    __syncthreads();
    int i = blockIdx.x * 256 + t;
    if (i == 0) ro[0] = 0;
    if (i < n) ro[i + 1] += pre[i >> 10];
}

// ---------------- fused: scatter (ns blocks) | gemm layer-0 (rest) ----------------
__global__ __launch_bounds__(256) void k_f3(const int* __restrict__ src, const int* __restrict__ dst,
                                            const int* __restrict__ ro, const int* __restrict__ rank,
                                            ushort_t* __restrict__ ssrc, int E, int ns,
                                            const void* __restrict__ actv,
                                            const ushort_t* __restrict__ W,
                                            ushort_t* __restrict__ hb,
                                            float* __restrict__ als, float* __restrict__ ald,
                                            const ushort_t* __restrict__ asrcp,
                                            const ushort_t* __restrict__ adstp,
                                            int N, const int* __restrict__ flag) {
    if ((int)blockIdx.x < ns) {
        int e0 = (blockIdx.x * 256 + threadIdx.x) * 4;
        if (e0 + 3 < E) {
            int4 d4 = *(const int4*)(dst + e0);
            int4 s4 = *(const int4*)(src + e0);
            int4 r4 = *(const int4*)(rank + e0);
            ssrc[ro[d4.x] + r4.x] = (ushort_t)s4.x;
            ssrc[ro[d4.y] + r4.y] = (ushort_t)s4.y;
            ssrc[ro[d4.z] + r4.z] = (ushort_t)s4.z;
            ssrc[ro[d4.w] + r4.w] = (ushort_t)s4.w;
        } else {
            for (int e = e0; e < E; e++) ssrc[ro[dst[e]] + rank[e]] = (ushort_t)src[e];
        }
    } else {
        gemm_body(blockIdx.x - ns, threadIdx.x, actv, W, hb, als, ald, asrcp, adstp, N, 0 /*layer0 handled via flag*/, flag);
    }
}

// layer-0 variant needs the f32 path; separate wrapper to pass layer0=1
__global__ __launch_bounds__(256) void k_f3_l0(const int* __restrict__ src, const int* __restrict__ dst,
                                               const int* __restrict__ ro, const int* __restrict__ rank,
                                               ushort_t* __restrict__ ssrc, int E, int ns,
                                               const void* __restrict__ actv,
                                               const ushort_t* __restrict__ W,
                                               ushort_t* __restrict__ hb,
                                               float* __restrict__ als, float* __restrict__ ald,
                                               const ushort_t* __restrict__ asrcp,
                                               const ushort_t* __restrict__ adstp,
                                               int N, const int* __restrict__ flag) {
    if ((int)blockIdx.x < ns) {
        int e0 = (blockIdx.x * 256 + threadIdx.x) * 4;
        if (e0 + 3 < E) {
            int4 d4 = *(const int4*)(dst + e0);
            int4 s4 = *(const int4*)(src + e0);
            int4 r4 = *(const int4*)(rank + e0);
            ssrc[ro[d4.x] + r4.x] = (ushort_t)s4.x;
            ssrc[ro[d4.y] + r4.y] = (ushort_t)s4.y;
            ssrc[ro[d4.z] + r4.z] = (ushort_t)s4.z;
            ssrc[ro[d4.w] + r4.w] = (ushort_t)s4.w;
        } else {
            for (int e = e0; e < E; e++) ssrc[ro[dst[e]] + rank[e]] = (ushort_t)src[e];
        }
    } else {
        gemm_body(blockIdx.x - ns, threadIdx.x, actv, W, hb, als, ald, asrcp, adstp, N, 1, flag);
    }
}

// ---------------- softmax + aggregation: 1 wave / node, 2 independent waves / block ----------------
// Single-pass (no max-sub; scores bounded so exp is fp32-safe). Dual accumulators break FMA chain.
__global__ __launch_bounds__(128) void k_agg(const int* __restrict__ ro,
                                             const ushort_t* __restrict__ ssrc,
                                             const ushort_t* __restrict__ hb,
                                             const float* __restrict__ als,
                                             const float* __restrict__ ald_,
                                             const ushort_t* __restrict__ bias,
                                             void* __restrict__ outp, int N, int apply_elu,
                                             int is_final, const int* __restrict__ flag) {
    __shared__ __align__(16) float wsm_all[2][256];
    __shared__ int osm_all[2][64];
    int wv = threadIdx.x >> 6, lane = threadIdx.x & 63;
    int n = blockIdx.x * 2 + wv;
    if (n >= N) return;                    // wave-uniform; no block barriers used
    float* wsm = wsm_all[wv];
    int* osm = osm_all[wv];
    int r0 = ro[n], r1 = ro[n + 1];
    floatx4 ad = *(const floatx4*)(ald_ + (size_t)n * 4);
    const char* alsb = (const char*)als;

    float a0 = 0.f, a1 = 0.f, b0 = 0.f, b1 = 0.f;
    float d0 = 0.f, d1 = 0.f, d2 = 0.f, d3 = 0.f;
    int hd = lane >> 4;
    int laneb = lane << 2;                 // byte offset of my 2 channels within a row
    for (int base = r0; base < r1; base += 64) {
        int i = base + lane;
        if (i < r1) {
            int s = ssrc[i];
            floatx4 as = *(const floatx4*)(alsb + (s << 4));
            float t0 = as.x + ad.x; float w0 = __expf(fmaxf(t0, NEG_SLOPE * t0)); d0 += w0;
            float t1 = as.y + ad.y; float w1 = __expf(fmaxf(t1, NEG_SLOPE * t1)); d1 += w1;
            float t2 = as.z + ad.z; float w2 = __expf(fmaxf(t2, NEG_SLOPE * t2)); d2 += w2;
            float t3 = as.w + ad.w; float w3 = __expf(fmaxf(t3, NEG_SLOPE * t3)); d3 += w3;
            osm[lane] = s << 8;            // row byte offset
            floatx4 w4 = {w0, w1, w2, w3};
            *(floatx4*)(wsm + lane * 4) = w4;
        }
        __builtin_amdgcn_wave_barrier();
        int cend = min(64, r1 - base);
        int j = 0;
        for (; j + 2 <= cend; j += 2) {
            float wj0 = wsm[j * 4 + hd];
            float wj1 = wsm[j * 4 + 4 + hd];
            uint32 h0 = *(const uint32*)((const char*)hb + (uint32)(osm[j] + laneb));
            uint32 h1 = *(const uint32*)((const char*)hb + (uint32)(osm[j + 1] + laneb));
            float2 p0 = bf2x(h0), p1 = bf2x(h1);
            a0 += wj0 * p0.x; a1 += wj0 * p0.y;
            b0 += wj1 * p1.x; b1 += wj1 * p1.y;
        }
        if (j < cend) {
            float wj0 = wsm[j * 4 + hd];
            uint32 h0 = *(const uint32*)((const char*)hb + (uint32)(osm[j] + laneb));
            float2 p0 = bf2x(h0);
            a0 += wj0 * p0.x; a1 += wj0 * p0.y;
        }
        __builtin_amdgcn_wave_barrier();
    }
    a0 += b0; a1 += b1;
    #pragma unroll
    for (int off = 32; off >= 1; off >>= 1) {
        d0 += __shfl_xor(d0, off); d1 += __shfl_xor(d1, off);
        d2 += __shfl_xor(d2, off); d3 += __shfl_xor(d3, off);
    }
    float den = (hd == 0 ? d0 : hd == 1 ? d1 : hd == 2 ? d2 : d3) + 1e-16f;
    float inv = 1.0f / den;
    int c0 = lane * 2;
    float2 bv = bf2x(*(const uint32*)(bias + c0));
    float o0 = a0 * inv + bv.x;
    float o1 = a1 * inv + bv.y;
    if (apply_elu) {
        o0 = o0 > 0.f ? o0 : expm1f(o0);
        o1 = o1 > 0.f ? o1 : expm1f(o1);
    }
    if (is_final && !flag[0]) {
        float2 o; o.x = o0; o.y = o1;
        *(float2*)((float*)outp + (size_t)n * 128 + c0) = o;
    } else {
        uint32 pack = (uint32)f2bf(o0) | ((uint32)f2bf(o1) << 16);
        *(uint32*)((ushort_t*)outp + (size_t)n * 128 + c0) = pack;
    }
}

extern "C" void kernel_launch(void* const* d_in, const int* in_sizes, int n_in,
                              void* d_out, int out_size, void* d_ws, size_t ws_size,
                              hipStream_t stream) {
    const void* x = d_in[0];
    const int* src = (const int*)d_in[1];
    const int* dst = (const int*)d_in[2];
    const int N = in_sizes[0] / 128;   // 50000 (< 65536 required for u16 ssrc)
    const int E = in_sizes[1];

    char* p = (char*)d_ws;
    auto alloc = [&](size_t bytes) { char* r = p; p += (bytes + 255) & ~(size_t)255; return r; };
    int*      flag  = (int*)alloc(256);
    int*      bsum  = (int*)alloc(256 * 4);
    int*      ro    = (int*)alloc((size_t)(N + 1) * 4);
    ushort_t* ssrc  = (ushort_t*)alloc((size_t)E * 2);         // aliases cnt (int[N]) early
    ushort_t* hb    = (ushort_t*)alloc((size_t)N * 128 * 2);
    float*    als   = (float*)alloc((size_t)N * 4 * 4);
    float*    ald   = (float*)alloc((size_t)N * 4 * 4);
    ushort_t* xact  = (ushort_t*)alloc((size_t)N * 128 * 2);   // aliases rank (int[E]) early
    ushort_t* pblk  = (ushort_t*)alloc((size_t)50304 * 2);

    int* cnt  = (int*)ssrc;    // dead once scatter overwrites ssrc
    int* rank = (int*)xact;    // dead once agg0 writes xact

    int g256e4 = (E + 1023) / 1024;
    int g256n = (N + 255) / 256;
    int nb = (N + 1023) / 1024;
    int gg = (N + 63) / 64;

    k_sniff<<<1, 256, 0, stream>>>((const uint32*)x, flag);
    hipMemsetAsync(cnt, 0, (size_t)N * 4, stream);
    k_f1<<<197 + g256e4, 256, 0, stream>>>(
        d_in[3], d_in[7], d_in[11],
        d_in[4], d_in[8], d_in[12],
        d_in[5], d_in[9], d_in[13],
        d_in[6], d_in[10], d_in[14],
        pblk, flag, dst, cnt, rank, E);
    k_scan_a<<<nb, 256, 0, stream>>>(cnt, ro, bsum, N);
    k_scan_bc<<<g256n, 256, 0, stream>>>(ro, bsum, N, nb);
    // scatter || gemm layer-0
    k_f3_l0<<<g256e4 + gg, 256, 0, stream>>>(src, dst, ro, rank, ssrc, E, g256e4,
        x, pblk, hb, als, ald, pblk + 49152, pblk + 49536, N, flag);

    int ga = (N + 1) / 2;
    for (int l = 0; l < 3; l++) {
        const ushort_t* As = pblk + 49152 + l * 128;
        const ushort_t* Ad = pblk + 49536 + l * 128;
        const ushort_t* Bc = pblk + 49920 + l * 128;
        void* outp = (l == 2) ? d_out : (void*)xact;
        if (l > 0) {
            const ushort_t* Wc = pblk + (size_t)l * 16384;
            k_gemm<<<gg, 256, 0, stream>>>(xact, Wc, hb, als, ald, As, Ad, N, flag);
        }
        k_agg<<<ga, 128, 0, stream>>>(ro, ssrc, hb, als, ald, Bc, outp, N, l < 2 ? 1 : 0,
                                      l == 2 ? 1 : 0, flag);
    }
}

// Round 8
// 358.160 us; speedup vs baseline: 1.0011x; 1.0011x over previous
//
#include <hip/hip_runtime.h>
#include <stdint.h>

typedef unsigned short ushort_t;
typedef unsigned int uint32;

typedef __attribute__((ext_vector_type(8))) short short8;
typedef __attribute__((ext_vector_type(4))) float floatx4;

#define NEG_SLOPE 0.2f

__device__ __forceinline__ ushort_t f2bf(float f) {
    union { float f; uint32 u; } v; v.f = f;
    uint32 u = v.u;
    uint32 r = (u + 0x7fffu + ((u >> 16) & 1u)) >> 16;
    return (ushort_t)r;
}
__device__ __forceinline__ float2 bf2x(uint32 u) {
    union { uint32 u; float f; } a, b;
    a.u = u << 16; b.u = u & 0xffff0000u;
    float2 r; r.x = a.f; r.y = b.f; return r;
}

// ---------------- dtype sniffer ----------------
__global__ void k_sniff(const uint32* __restrict__ x, int* __restrict__ flag) {
    __shared__ int sh[256];
    int t = threadIdx.x;
    int c = 0;
    for (int i = t; i < 1024; i += 256) {
        uint32 h = x[i] & 0xFFFFu;
        uint32 e = (h >> 7) & 0xFFu;
        if (h == 0u || (e >= 100u && e <= 140u)) c++;
    }
    sh[t] = c; __syncthreads();
    for (int off = 128; off >= 1; off >>= 1) {
        if (t < off) sh[t] += sh[t + off];
        __syncthreads();
    }
    if (t == 0) flag[0] = (sh[0] >= 512) ? 1 : 0;
}

// ---------------- GEMM body ----------------
__device__ __forceinline__ void gemm_body(int bid, int tid,
                                          const void* __restrict__ actv,
                                          const ushort_t* __restrict__ W,
                                          ushort_t* __restrict__ hb,
                                          float* __restrict__ als,
                                          float* __restrict__ ald,
                                          const ushort_t* __restrict__ asrcp,
                                          const ushort_t* __restrict__ adstp,
                                          int N, int layer0,
                                          const int* __restrict__ flag) {
    int wid = tid >> 6, lane = tid & 63;
    int n0 = (bid * 4 + wid) * 16;
    int mrow = lane & 15, quad = lane >> 4;
    int n = n0 + mrow;
    bool isf32 = (layer0 && !flag[0]);
    short8 a[4];
    if (n < N) {
        if (isf32) {
            const float* ar = (const float*)actv + (size_t)n * 128 + quad * 8;
            #pragma unroll
            for (int kt = 0; kt < 4; kt++) {
                float4 fa = *(const float4*)(ar + kt * 32);
                float4 fb = *(const float4*)(ar + kt * 32 + 4);
                short8 v;
                v[0] = (short)f2bf(fa.x); v[1] = (short)f2bf(fa.y);
                v[2] = (short)f2bf(fa.z); v[3] = (short)f2bf(fa.w);
                v[4] = (short)f2bf(fb.x); v[5] = (short)f2bf(fb.y);
                v[6] = (short)f2bf(fb.z); v[7] = (short)f2bf(fb.w);
                a[kt] = v;
            }
        } else {
            const ushort_t* ar = (const ushort_t*)actv + (size_t)n * 128 + quad * 8;
            #pragma unroll
            for (int kt = 0; kt < 4; kt++) a[kt] = *(const short8*)(ar + kt * 32);
        }
    } else {
        #pragma unroll
        for (int kt = 0; kt < 4; kt++) { short8 z = {0,0,0,0,0,0,0,0}; a[kt] = z; }
    }
    float ps[4], pd[4];
    #pragma unroll
    for (int t = 0; t < 8; t++) {
        if ((t & 1) == 0) {
            #pragma unroll
            for (int r = 0; r < 4; r++) { ps[r] = 0.f; pd[r] = 0.f; }
        }
        const ushort_t* wr = W + (size_t)(t * 16 + mrow) * 128 + quad * 8;
        floatx4 acc = {0.f, 0.f, 0.f, 0.f};
        #pragma unroll
        for (int kt = 0; kt < 4; kt++) {
            short8 b = *(const short8*)(wr + kt * 32);
            acc = __builtin_amdgcn_mfma_f32_16x16x32_bf16(a[kt], b, acc, 0, 0, 0);
        }
        int col = t * 16 + mrow;
        union { uint32 u; float f; } cs, cd;
        cs.u = ((uint32)asrcp[col]) << 16;
        cd.u = ((uint32)adstp[col]) << 16;
        #pragma unroll
        for (int r = 0; r < 4; r++) {
            int rn = n0 + quad * 4 + r;
            if (rn < N) hb[(size_t)rn * 128 + col] = f2bf(acc[r]);
            ps[r] += acc[r] * cs.f;
            pd[r] += acc[r] * cd.f;
        }
        if (t & 1) {
            #pragma unroll
            for (int off = 1; off <= 8; off <<= 1) {
                #pragma unroll
                for (int r = 0; r < 4; r++) {
                    ps[r] += __shfl_xor(ps[r], off);
                    pd[r] += __shfl_xor(pd[r], off);
                }
            }
            int h = t >> 1;
            if (mrow < 8) {
                int r = mrow & 3;
                float vs = r == 0 ? ps[0] : r == 1 ? ps[1] : r == 2 ? ps[2] : ps[3];
                float vd = r == 0 ? pd[0] : r == 1 ? pd[1] : r == 2 ? pd[2] : pd[3];
                int rn = n0 + quad * 4 + r;
                if (rn < N) {
                    float* dp = (mrow < 4) ? als : ald;
                    dp[(size_t)rn * 4 + h] = (mrow < 4) ? vs : vd;
                }
            }
        }
    }
}

__global__ __launch_bounds__(256) void k_gemm(const void* __restrict__ actv,
                                              const ushort_t* __restrict__ W,
                                              ushort_t* __restrict__ hb,
                                              float* __restrict__ als,
                                              float* __restrict__ ald,
                                              const ushort_t* __restrict__ asrcp,
                                              const ushort_t* __restrict__ adstp,
                                              int N, const int* __restrict__ flag) {
    gemm_body(blockIdx.x, threadIdx.x, actv, W, hb, als, ald, asrcp, adstp, N, 0, flag);
}

// ---------------- fused: param canonicalization (197 blocks) | hist x4-unrolled (rest) ----------------
__global__ void k_f1(const void* W0, const void* W1, const void* W2,
                     const void* s0, const void* s1, const void* s2,
                     const void* a0, const void* a1, const void* a2,
                     const void* b0, const void* b1, const void* b2,
                     ushort_t* __restrict__ pblk, const int* __restrict__ flag,
                     const int* __restrict__ dst, int* __restrict__ cnt,
                     int* __restrict__ rank, int E) {
    if (blockIdx.x < 197) {
        int i = blockIdx.x * 256 + threadIdx.x;
        if (i >= 50304) return;
        const void* src; int off;
        if (i < 49152) {
            int seg = i / 16384; off = i % 16384;
            src = seg == 0 ? W0 : seg == 1 ? W1 : W2;
        } else if (i < 49536) {
            int j = i - 49152; int seg = j / 128; off = j % 128;
            src = seg == 0 ? s0 : seg == 1 ? s1 : s2;
        } else if (i < 49920) {
            int j = i - 49536; int seg = j / 128; off = j % 128;
            src = seg == 0 ? a0 : seg == 1 ? a1 : a2;
        } else {
            int j = i - 49920; int seg = j / 128; off = j % 128;
            src = seg == 0 ? b0 : seg == 1 ? b1 : b2;
        }
        if (flag[0]) pblk[i] = ((const ushort_t*)src)[off];
        else         pblk[i] = f2bf(((const float*)src)[off]);
    } else {
        int e0 = ((blockIdx.x - 197) * 256 + threadIdx.x) * 4;
        if (e0 + 3 < E) {
            int4 d4 = *(const int4*)(dst + e0);
            int r0 = atomicAdd(&cnt[d4.x], 1);
            int r1 = atomicAdd(&cnt[d4.y], 1);
            int r2 = atomicAdd(&cnt[d4.z], 1);
            int r3 = atomicAdd(&cnt[d4.w], 1);
            int4 r4 = {r0, r1, r2, r3};
            *(int4*)(rank + e0) = r4;
        } else {
            for (int e = e0; e < E; e++) rank[e] = atomicAdd(&cnt[dst[e]], 1);
        }
    }
}

// ---------------- fused: scan_a (nb blocks) | gemm layer-0 (rest) ----------------
__global__ __launch_bounds__(256) void k_f2(const int* __restrict__ cnt, int* __restrict__ ro,
                                            int* __restrict__ bsum, int n, int nb,
                                            const void* __restrict__ actv,
                                            const ushort_t* __restrict__ W,
                                            ushort_t* __restrict__ hb,
                                            float* __restrict__ als, float* __restrict__ ald,
                                            const ushort_t* __restrict__ asrcp,
                                            const ushort_t* __restrict__ adstp,
                                            int N, const int* __restrict__ flag) {
    if ((int)blockIdx.x < nb) {
        __shared__ int sd[256];
        int t = threadIdx.x;
        int base = blockIdx.x * 1024 + t * 4;
        int v0 = (base + 0 < n) ? cnt[base + 0] : 0;
        int v1 = (base + 1 < n) ? cnt[base + 1] : 0;
        int v2 = (base + 2 < n) ? cnt[base + 2] : 0;
        int v3 = (base + 3 < n) ? cnt[base + 3] : 0;
        int s = v0 + v1 + v2 + v3;
        sd[t] = s; __syncthreads();
        for (int off = 1; off < 256; off <<= 1) {
            int x = 0;
            if (t >= off) x = sd[t - off];
            __syncthreads();
            sd[t] += x;
            __syncthreads();
        }
        int run = sd[t] - s;
        run += v0; if (base + 0 < n) ro[base + 1] = run;
        run += v1; if (base + 1 < n) ro[base + 2] = run;
        run += v2; if (base + 2 < n) ro[base + 3] = run;
        run += v3; if (base + 3 < n) ro[base + 4] = run;
        if (t == 255) bsum[blockIdx.x] = sd[255];
    } else {
        gemm_body(blockIdx.x - nb, threadIdx.x, actv, W, hb, als, ald, asrcp, adstp, N, 1, flag);
    }
}

__global__ void k_scan_bc(int* __restrict__ ro, const int* __restrict__ bsum,
                          int n, int nb) {
    __shared__ int pre[256];
    int t = threadIdx.x;
    if (t == 0) {
        int acc = 0;
        for (int b = 0; b < nb; b++) { pre[b] = acc; acc += bsum[b]; }
    }
    __syncthreads();
    int i = blockIdx.x * 256 + t;
    if (i == 0) ro[0] = 0;
    if (i < n) ro[i + 1] += pre[i >> 10];
}

// atomic-free scatter; u16 node indices (requires N < 65536); x4 unrolled
__global__ void k_scatter(const int* __restrict__ src, const int* __restrict__ dst,
                          const int* __restrict__ ro, const int* __restrict__ rank,
                          ushort_t* __restrict__ ssrc, int E) {
    int e0 = (blockIdx.x * 256 + threadIdx.x) * 4;
    if (e0 + 3 < E) {
        int4 d4 = *(const int4*)(dst + e0);
        int4 s4 = *(const int4*)(src + e0);
        int4 r4 = *(const int4*)(rank + e0);
        ssrc[ro[d4.x] + r4.x] = (ushort_t)s4.x;
        ssrc[ro[d4.y] + r4.y] = (ushort_t)s4.y;
        ssrc[ro[d4.z] + r4.z] = (ushort_t)s4.z;
        ssrc[ro[d4.w] + r4.w] = (ushort_t)s4.w;
    } else {
        for (int e = e0; e < E; e++) ssrc[ro[dst[e]] + rank[e]] = (ushort_t)src[e];
    }
}

// ---------------- softmax + aggregation: 1 wave per (node, head-pair) ----------------
// blockIdx = n*2 + hp; hp=0 -> heads {0,1} (channels 0..63), hp=1 -> heads {2,3}.
// Lane halves process 2 edges per trip; each lane covers 2 channels of a 128B half-row.
// Single-pass softmax (scores bounded; exp fp32-safe). Dual accumulators break FMA chain.
__global__ __launch_bounds__(64) void k_agg(const int* __restrict__ ro,
                                            const ushort_t* __restrict__ ssrc,
                                            const ushort_t* __restrict__ hb,
                                            const float* __restrict__ als,
                                            const float* __restrict__ ald_,
                                            const ushort_t* __restrict__ bias,
                                            void* __restrict__ outp, int N, int apply_elu,
                                            int is_final, const int* __restrict__ flag) {
    int bid = blockIdx.x;
    int n = bid >> 1;
    int hp = bid & 1;
    int lane = threadIdx.x;
    int r0 = ro[n], r1 = ro[n + 1];
    float2 adp = *(const float2*)(ald_ + (size_t)n * 4 + hp * 2);
    const char* alsb = (const char*)als + hp * 8;

    __shared__ __align__(8) float wsm[128];   // 64 edges x 2 heads
    __shared__ int osm[64];
    float a0 = 0.f, a1 = 0.f, b0 = 0.f, b1 = 0.f;
    float d0 = 0.f, d1 = 0.f;
    int eh = lane >> 5;                 // edge-half selector
    int l5 = lane & 31;
    int hd2 = l5 >> 4;                  // which of my 2 heads
    int chb = hp * 128 + l5 * 4;        // byte offset of my 2 channels within a row

    for (int base = r0; base < r1; base += 64) {
        int i = base + lane;
        int cend = min(64, r1 - base);
        if (i < r1) {
            int s = ssrc[i];
            float2 as = *(const float2*)(alsb + (s << 4));
            float t0 = as.x + adp.x; float w0 = __expf(fmaxf(t0, NEG_SLOPE * t0)); d0 += w0;
            float t1 = as.y + adp.y; float w1 = __expf(fmaxf(t1, NEG_SLOPE * t1)); d1 += w1;
            osm[lane] = s << 8;         // row byte offset
            float2 w2v; w2v.x = w0; w2v.y = w1;
            *(float2*)(wsm + lane * 2) = w2v;
        } else if (lane == cend) {      // zero-pad slot for the odd-tail trip
            osm[lane] = 0;
            float2 z; z.x = 0.f; z.y = 0.f;
            *(float2*)(wsm + lane * 2) = z;
        }
        __builtin_amdgcn_wave_barrier();
        int trips = (cend + 1) >> 1;    // 2 edges per trip (one per lane-half)
        int j2 = 0;
        for (; j2 + 2 <= trips; j2 += 2) {
            int e0i = j2 * 2 + eh;
            int e1i = j2 * 2 + 2 + eh;
            float wj0 = wsm[e0i * 2 + hd2];
            float wj1 = wsm[e1i * 2 + hd2];
            uint32 h0 = *(const uint32*)((const char*)hb + (uint32)(osm[e0i] + chb));
            uint32 h1 = *(const uint32*)((const char*)hb + (uint32)(osm[e1i] + chb));
            float2 p0 = bf2x(h0), p1 = bf2x(h1);
            a0 += wj0 * p0.x; a1 += wj0 * p0.y;
            b0 += wj1 * p1.x; b1 += wj1 * p1.y;
        }
        if (j2 < trips) {
            int e0i = j2 * 2 + eh;
            float wj0 = wsm[e0i * 2 + hd2];
            uint32 h0 = *(const uint32*)((const char*)hb + (uint32)(osm[e0i] + chb));
            float2 p0 = bf2x(h0);
            a0 += wj0 * p0.x; a1 += wj0 * p0.y;
        }
        __builtin_amdgcn_wave_barrier();
    }
    a0 += b0; a1 += b1;
    // merge the two edge-halves (same channels, disjoint edges)
    a0 += __shfl_xor(a0, 32); a1 += __shfl_xor(a1, 32);
    // full-wave denominator reduce (each edge counted once across lanes)
    #pragma unroll
    for (int off = 32; off >= 1; off >>= 1) {
        d0 += __shfl_xor(d0, off);
        d1 += __shfl_xor(d1, off);
    }
    if (eh == 0) {
        float den = (hd2 == 0 ? d0 : d1) + 1e-16f;
        float inv = 1.0f / den;
        float2 bv = bf2x(*(const uint32*)((const char*)bias + chb));
        float o0 = a0 * inv + bv.x;
        float o1 = a1 * inv + bv.y;
        if (apply_elu) {
            o0 = o0 > 0.f ? o0 : expm1f(o0);
            o1 = o1 > 0.f ? o1 : expm1f(o1);
        }
        if (is_final && !flag[0]) {
            float2 o; o.x = o0; o.y = o1;
            *(float2*)((char*)outp + (size_t)n * 512 + chb * 2) = o;
        } else {
            uint32 pack = (uint32)f2bf(o0) | ((uint32)f2bf(o1) << 16);
            *(uint32*)((char*)outp + (size_t)n * 256 + chb) = pack;
        }
    }
}

extern "C" void kernel_launch(void* const* d_in, const int* in_sizes, int n_in,
                              void* d_out, int out_size, void* d_ws, size_t ws_size,
                              hipStream_t stream) {
    const void* x = d_in[0];
    const int* src = (const int*)d_in[1];
    const int* dst = (const int*)d_in[2];
    const int N = in_sizes[0] / 128;   // 50000 (< 65536 required for u16 ssrc)
    const int E = in_sizes[1];

    char* p = (char*)d_ws;
    auto alloc = [&](size_t bytes) { char* r = p; p += (bytes + 255) & ~(size_t)255; return r; };
    int*      flag  = (int*)alloc(256);
    int*      bsum  = (int*)alloc(256 * 4);
    int*      ro    = (int*)alloc((size_t)(N + 1) * 4);
    ushort_t* ssrc  = (ushort_t*)alloc((size_t)E * 2);         // aliases cnt (int[N]) early
    ushort_t* hb    = (ushort_t*)alloc((size_t)N * 128 * 2);
    float*    als   = (float*)alloc((size_t)N * 4 * 4);
    float*    ald   = (float*)alloc((size_t)N * 4 * 4);
    ushort_t* xact  = (ushort_t*)alloc((size_t)N * 128 * 2);   // aliases rank (int[E]) early
    ushort_t* pblk  = (ushort_t*)alloc((size_t)50304 * 2);

    int* cnt  = (int*)ssrc;    // dead once scatter overwrites ssrc
    int* rank = (int*)xact;    // dead once agg0 writes xact

    int g256e4 = (E + 1023) / 1024;
    int g256n = (N + 255) / 256;
    int nb = (N + 1023) / 1024;
    int gg = (N + 63) / 64;

    k_sniff<<<1, 256, 0, stream>>>((const uint32*)x, flag);
    hipMemsetAsync(cnt, 0, (size_t)N * 4, stream);
    k_f1<<<197 + g256e4, 256, 0, stream>>>(
        d_in[3], d_in[7], d_in[11],
        d_in[4], d_in[8], d_in[12],
        d_in[5], d_in[9], d_in[13],
        d_in[6], d_in[10], d_in[14],
        pblk, flag, dst, cnt, rank, E);
    k_f2<<<nb + gg, 256, 0, stream>>>(cnt, ro, bsum, N, nb,
        x, pblk, hb, als, ald, pblk + 49152, pblk + 49536, N, flag);
    k_scan_bc<<<g256n, 256, 0, stream>>>(ro, bsum, N, nb);
    k_scatter<<<g256e4, 256, 0, stream>>>(src, dst, ro, rank, ssrc, E);

    for (int l = 0; l < 3; l++) {
        const ushort_t* As = pblk + 49152 + l * 128;
        const ushort_t* Ad = pblk + 49536 + l * 128;
        const ushort_t* Bc = pblk + 49920 + l * 128;
        void* outp = (l == 2) ? d_out : (void*)xact;
        if (l > 0) {
            const ushort_t* Wc = pblk + (size_t)l * 16384;
            k_gemm<<<gg, 256, 0, stream>>>(xact, Wc, hb, als, ald, As, Ad, N, flag);
        }
        k_agg<<<N * 2, 64, 0, stream>>>(ro, ssrc, hb, als, ald, Bc, outp, N, l < 2 ? 1 : 0,
                                        l == 2 ? 1 : 0, flag);
    }
}

// Round 9
// 337.043 us; speedup vs baseline: 1.0638x; 1.0627x over previous
//
#include <hip/hip_runtime.h>
#include <stdint.h>

typedef unsigned short ushort_t;
typedef unsigned int uint32;

typedef __attribute__((ext_vector_type(8))) short short8;
typedef __attribute__((ext_vector_type(4))) float floatx4;

#define NEG_SLOPE 0.2f

__device__ __forceinline__ ushort_t f2bf(float f) {
    union { float f; uint32 u; } v; v.f = f;
    uint32 u = v.u;
    uint32 r = (u + 0x7fffu + ((u >> 16) & 1u)) >> 16;
    return (ushort_t)r;
}
__device__ __forceinline__ float2 bf2x(uint32 u) {
    union { uint32 u; float f; } a, b;
    a.u = u << 16; b.u = u & 0xffff0000u;
    float2 r; r.x = a.f; r.y = b.f; return r;
}

// ---------------- dtype sniffer ----------------
__global__ void k_sniff(const uint32* __restrict__ x, int* __restrict__ flag) {
    __shared__ int sh[256];
    int t = threadIdx.x;
    int c = 0;
    for (int i = t; i < 1024; i += 256) {
        uint32 h = x[i] & 0xFFFFu;
        uint32 e = (h >> 7) & 0xFFu;
        if (h == 0u || (e >= 100u && e <= 140u)) c++;
    }
    sh[t] = c; __syncthreads();
    for (int off = 128; off >= 1; off >>= 1) {
        if (t < off) sh[t] += sh[t + off];
        __syncthreads();
    }
    if (t == 0) flag[0] = (sh[0] >= 512) ? 1 : 0;
}

// ---------------- GEMM body ----------------
__device__ __forceinline__ void gemm_body(int bid, int tid,
                                          const void* __restrict__ actv,
                                          const ushort_t* __restrict__ W,
                                          ushort_t* __restrict__ hb,
                                          float* __restrict__ als,
                                          float* __restrict__ ald,
                                          const ushort_t* __restrict__ asrcp,
                                          const ushort_t* __restrict__ adstp,
                                          int N, int layer0,
                                          const int* __restrict__ flag) {
    int wid = tid >> 6, lane = tid & 63;
    int n0 = (bid * 4 + wid) * 16;
    int mrow = lane & 15, quad = lane >> 4;
    int n = n0 + mrow;
    bool isf32 = (layer0 && !flag[0]);
    short8 a[4];
    if (n < N) {
        if (isf32) {
            const float* ar = (const float*)actv + (size_t)n * 128 + quad * 8;
            #pragma unroll
            for (int kt = 0; kt < 4; kt++) {
                float4 fa = *(const float4*)(ar + kt * 32);
                float4 fb = *(const float4*)(ar + kt * 32 + 4);
                short8 v;
                v[0] = (short)f2bf(fa.x); v[1] = (short)f2bf(fa.y);
                v[2] = (short)f2bf(fa.z); v[3] = (short)f2bf(fa.w);
                v[4] = (short)f2bf(fb.x); v[5] = (short)f2bf(fb.y);
                v[6] = (short)f2bf(fb.z); v[7] = (short)f2bf(fb.w);
                a[kt] = v;
            }
        } else {
            const ushort_t* ar = (const ushort_t*)actv + (size_t)n * 128 + quad * 8;
            #pragma unroll
            for (int kt = 0; kt < 4; kt++) a[kt] = *(const short8*)(ar + kt * 32);
        }
    } else {
        #pragma unroll
        for (int kt = 0; kt < 4; kt++) { short8 z = {0,0,0,0,0,0,0,0}; a[kt] = z; }
    }
    float ps[4], pd[4];
    #pragma unroll
    for (int t = 0; t < 8; t++) {
        if ((t & 1) == 0) {
            #pragma unroll
            for (int r = 0; r < 4; r++) { ps[r] = 0.f; pd[r] = 0.f; }
        }
        const ushort_t* wr = W + (size_t)(t * 16 + mrow) * 128 + quad * 8;
        floatx4 acc = {0.f, 0.f, 0.f, 0.f};
        #pragma unroll
        for (int kt = 0; kt < 4; kt++) {
            short8 b = *(const short8*)(wr + kt * 32);
            acc = __builtin_amdgcn_mfma_f32_16x16x32_bf16(a[kt], b, acc, 0, 0, 0);
        }
        int col = t * 16 + mrow;
        union { uint32 u; float f; } cs, cd;
        cs.u = ((uint32)asrcp[col]) << 16;
        cd.u = ((uint32)adstp[col]) << 16;
        #pragma unroll
        for (int r = 0; r < 4; r++) {
            int rn = n0 + quad * 4 + r;
            if (rn < N) hb[(size_t)rn * 128 + col] = f2bf(acc[r]);
            ps[r] += acc[r] * cs.f;
            pd[r] += acc[r] * cd.f;
        }
        if (t & 1) {
            #pragma unroll
            for (int off = 1; off <= 8; off <<= 1) {
                #pragma unroll
                for (int r = 0; r < 4; r++) {
                    ps[r] += __shfl_xor(ps[r], off);
                    pd[r] += __shfl_xor(pd[r], off);
                }
            }
            int h = t >> 1;
            if (mrow < 8) {
                int r = mrow & 3;
                float vs = r == 0 ? ps[0] : r == 1 ? ps[1] : r == 2 ? ps[2] : ps[3];
                float vd = r == 0 ? pd[0] : r == 1 ? pd[1] : r == 2 ? pd[2] : pd[3];
                int rn = n0 + quad * 4 + r;
                if (rn < N) {
                    float* dp = (mrow < 4) ? als : ald;
                    dp[(size_t)rn * 4 + h] = (mrow < 4) ? vs : vd;
                }
            }
        }
    }
}

__global__ __launch_bounds__(256) void k_gemm(const void* __restrict__ actv,
                                              const ushort_t* __restrict__ W,
                                              ushort_t* __restrict__ hb,
                                              float* __restrict__ als,
                                              float* __restrict__ ald,
                                              const ushort_t* __restrict__ asrcp,
                                              const ushort_t* __restrict__ adstp,
                                              int N, const int* __restrict__ flag) {
    gemm_body(blockIdx.x, threadIdx.x, actv, W, hb, als, ald, asrcp, adstp, N, 0, flag);
}

// ---------------- fused: param canonicalization (197 blocks) | hist x4-unrolled (rest) ----------------
__global__ void k_f1(const void* W0, const void* W1, const void* W2,
                     const void* s0, const void* s1, const void* s2,
                     const void* a0, const void* a1, const void* a2,
                     const void* b0, const void* b1, const void* b2,
                     ushort_t* __restrict__ pblk, const int* __restrict__ flag,
                     const int* __restrict__ dst, int* __restrict__ cnt,
                     int* __restrict__ rank, int E) {
    if (blockIdx.x < 197) {
        int i = blockIdx.x * 256 + threadIdx.x;
        if (i >= 50304) return;
        const void* src; int off;
        if (i < 49152) {
            int seg = i / 16384; off = i % 16384;
            src = seg == 0 ? W0 : seg == 1 ? W1 : W2;
        } else if (i < 49536) {
            int j = i - 49152; int seg = j / 128; off = j % 128;
            src = seg == 0 ? s0 : seg == 1 ? s1 : s2;
        } else if (i < 49920) {
            int j = i - 49536; int seg = j / 128; off = j % 128;
            src = seg == 0 ? a0 : seg == 1 ? a1 : a2;
        } else {
            int j = i - 49920; int seg = j / 128; off = j % 128;
            src = seg == 0 ? b0 : seg == 1 ? b1 : b2;
        }
        if (flag[0]) pblk[i] = ((const ushort_t*)src)[off];
        else         pblk[i] = f2bf(((const float*)src)[off]);
    } else {
        int e0 = ((blockIdx.x - 197) * 256 + threadIdx.x) * 4;
        if (e0 + 3 < E) {
            int4 d4 = *(const int4*)(dst + e0);
            int r0 = atomicAdd(&cnt[d4.x], 1);
            int r1 = atomicAdd(&cnt[d4.y], 1);
            int r2 = atomicAdd(&cnt[d4.z], 1);
            int r3 = atomicAdd(&cnt[d4.w], 1);
            int4 r4 = {r0, r1, r2, r3};
            *(int4*)(rank + e0) = r4;
        } else {
            for (int e = e0; e < E; e++) rank[e] = atomicAdd(&cnt[dst[e]], 1);
        }
    }
}

// ---------------- fused: scan_a (nb blocks) | gemm layer-0 (rest) ----------------
__global__ __launch_bounds__(256) void k_f2(const int* __restrict__ cnt, int* __restrict__ ro,
                                            int* __restrict__ bsum, int n, int nb,
                                            const void* __restrict__ actv,
                                            const ushort_t* __restrict__ W,
                                            ushort_t* __restrict__ hb,
                                            float* __restrict__ als, float* __restrict__ ald,
                                            const ushort_t* __restrict__ asrcp,
                                            const ushort_t* __restrict__ adstp,
                                            int N, const int* __restrict__ flag) {
    if ((int)blockIdx.x < nb) {
        __shared__ int sd[256];
        int t = threadIdx.x;
        int base = blockIdx.x * 1024 + t * 4;
        int v0 = (base + 0 < n) ? cnt[base + 0] : 0;
        int v1 = (base + 1 < n) ? cnt[base + 1] : 0;
        int v2 = (base + 2 < n) ? cnt[base + 2] : 0;
        int v3 = (base + 3 < n) ? cnt[base + 3] : 0;
        int s = v0 + v1 + v2 + v3;
        sd[t] = s; __syncthreads();
        for (int off = 1; off < 256; off <<= 1) {
            int x = 0;
            if (t >= off) x = sd[t - off];
            __syncthreads();
            sd[t] += x;
            __syncthreads();
        }
        int run = sd[t] - s;
        run += v0; if (base + 0 < n) ro[base + 1] = run;
        run += v1; if (base + 1 < n) ro[base + 2] = run;
        run += v2; if (base + 2 < n) ro[base + 3] = run;
        run += v3; if (base + 3 < n) ro[base + 4] = run;
        if (t == 255) bsum[blockIdx.x] = sd[255];
    } else {
        gemm_body(blockIdx.x - nb, threadIdx.x, actv, W, hb, als, ald, asrcp, adstp, N, 1, flag);
    }
}

__global__ void k_scan_bc(int* __restrict__ ro, const int* __restrict__ bsum,
                          int n, int nb) {
    __shared__ int pre[256];
    int t = threadIdx.x;
    if (t == 0) {
        int acc = 0;
        for (int b = 0; b < nb; b++) { pre[b] = acc; acc += bsum[b]; }
    }
    __syncthreads();
    int i = blockIdx.x * 256 + t;
    if (i == 0) ro[0] = 0;
    if (i < n) ro[i + 1] += pre[i >> 10];
}

// atomic-free scatter; u16 node indices (requires N < 65536); x4 unrolled
__global__ void k_scatter(const int* __restrict__ src, const int* __restrict__ dst,
                          const int* __restrict__ ro, const int* __restrict__ rank,
                          ushort_t* __restrict__ ssrc, int E) {
    int e0 = (blockIdx.x * 256 + threadIdx.x) * 4;
    if (e0 + 3 < E) {
        int4 d4 = *(const int4*)(dst + e0);
        int4 s4 = *(const int4*)(src + e0);
        int4 r4 = *(const int4*)(rank + e0);
        ssrc[ro[d4.x] + r4.x] = (ushort_t)s4.x;
        ssrc[ro[d4.y] + r4.y] = (ushort_t)s4.y;
        ssrc[ro[d4.z] + r4.z] = (ushort_t)s4.z;
        ssrc[ro[d4.w] + r4.w] = (ushort_t)s4.w;
    } else {
        for (int e = e0; e < E; e++) ssrc[ro[dst[e]] + rank[e]] = (ushort_t)src[e];
    }
}

// ---------------- softmax + aggregation: 1 wave handles 2 adjacent nodes sequentially ----------------
// Single-pass (no max-sub; scores bounded so exp is fp32-safe). R6-measured-best body,
// wrapped in a 2-node loop to halve block count (amortize per-block fixed cost / CP dispatch).
__global__ __launch_bounds__(64) void k_agg(const int* __restrict__ ro,
                                            const ushort_t* __restrict__ ssrc,
                                            const ushort_t* __restrict__ hb,
                                            const float* __restrict__ als,
                                            const float* __restrict__ ald_,
                                            const ushort_t* __restrict__ bias,
                                            void* __restrict__ outp, int N, int apply_elu,
                                            int is_final, const int* __restrict__ flag) {
    int lane = threadIdx.x;
    int nbase = blockIdx.x * 2;
    const char* alsb = (const char*)als;

    __shared__ __align__(16) float wsm[256];
    __shared__ int osm[64];
    int hd = lane >> 4;
    int laneb = lane << 2;                 // byte offset of my 2 channels within a row
    int c0 = lane * 2;
    float2 bv = bf2x(*(const uint32*)(bias + c0));

    #pragma unroll
    for (int rep = 0; rep < 2; rep++) {
        int n = nbase + rep;
        if (n >= N) return;
        int r0 = ro[n], r1 = ro[n + 1];
        floatx4 ad = *(const floatx4*)(ald_ + (size_t)n * 4);

        float a0 = 0.f, a1 = 0.f;
        float d0 = 0.f, d1 = 0.f, d2 = 0.f, d3 = 0.f;
        for (int base = r0; base < r1; base += 64) {
            int i = base + lane;
            if (i < r1) {
                int s = ssrc[i];
                floatx4 as = *(const floatx4*)(alsb + (s << 4));
                float t0 = as.x + ad.x; float w0 = __expf(fmaxf(t0, NEG_SLOPE * t0)); d0 += w0;
                float t1 = as.y + ad.y; float w1 = __expf(fmaxf(t1, NEG_SLOPE * t1)); d1 += w1;
                float t2 = as.z + ad.z; float w2 = __expf(fmaxf(t2, NEG_SLOPE * t2)); d2 += w2;
                float t3 = as.w + ad.w; float w3 = __expf(fmaxf(t3, NEG_SLOPE * t3)); d3 += w3;
                osm[lane] = s << 8;        // row byte offset
                floatx4 w4 = {w0, w1, w2, w3};
                *(floatx4*)(wsm + lane * 4) = w4;
            }
            __builtin_amdgcn_wave_barrier();
            int cend = min(64, r1 - base);
            #pragma unroll 4
            for (int j = 0; j < cend; j++) {
                float wj = wsm[j * 4 + hd];
                uint32 h2 = *(const uint32*)((const char*)hb + (uint32)(osm[j] + laneb));
                float2 p = bf2x(h2);
                a0 += wj * p.x;
                a1 += wj * p.y;
            }
            __builtin_amdgcn_wave_barrier();
        }
        #pragma unroll
        for (int off = 32; off >= 1; off >>= 1) {
            d0 += __shfl_xor(d0, off); d1 += __shfl_xor(d1, off);
            d2 += __shfl_xor(d2, off); d3 += __shfl_xor(d3, off);
        }
        float den = (hd == 0 ? d0 : hd == 1 ? d1 : hd == 2 ? d2 : d3) + 1e-16f;
        float inv = 1.0f / den;
        float o0 = a0 * inv + bv.x;
        float o1 = a1 * inv + bv.y;
        if (apply_elu) {
            o0 = o0 > 0.f ? o0 : expm1f(o0);
            o1 = o1 > 0.f ? o1 : expm1f(o1);
        }
        if (is_final && !flag[0]) {
            float2 o; o.x = o0; o.y = o1;
            *(float2*)((float*)outp + (size_t)n * 128 + c0) = o;
        } else {
            uint32 pack = (uint32)f2bf(o0) | ((uint32)f2bf(o1) << 16);
            *(uint32*)((ushort_t*)outp + (size_t)n * 128 + c0) = pack;
        }
    }
}

extern "C" void kernel_launch(void* const* d_in, const int* in_sizes, int n_in,
                              void* d_out, int out_size, void* d_ws, size_t ws_size,
                              hipStream_t stream) {
    const void* x = d_in[0];
    const int* src = (const int*)d_in[1];
    const int* dst = (const int*)d_in[2];
    const int N = in_sizes[0] / 128;   // 50000 (< 65536 required for u16 ssrc)
    const int E = in_sizes[1];

    char* p = (char*)d_ws;
    auto alloc = [&](size_t bytes) { char* r = p; p += (bytes + 255) & ~(size_t)255; return r; };
    int*      flag  = (int*)alloc(256);
    int*      bsum  = (int*)alloc(256 * 4);
    int*      ro    = (int*)alloc((size_t)(N + 1) * 4);
    ushort_t* ssrc  = (ushort_t*)alloc((size_t)E * 2);         // aliases cnt (int[N]) early
    ushort_t* hb    = (ushort_t*)alloc((size_t)N * 128 * 2);
    float*    als   = (float*)alloc((size_t)N * 4 * 4);
    float*    ald   = (float*)alloc((size_t)N * 4 * 4);
    ushort_t* xact  = (ushort_t*)alloc((size_t)N * 128 * 2);   // aliases rank (int[E]) early
    ushort_t* pblk  = (ushort_t*)alloc((size_t)50304 * 2);

    int* cnt  = (int*)ssrc;    // dead once scatter overwrites ssrc
    int* rank = (int*)xact;    // dead once agg0 writes xact

    int g256e4 = (E + 1023) / 1024;
    int g256n = (N + 255) / 256;
    int nb = (N + 1023) / 1024;
    int gg = (N + 63) / 64;

    k_sniff<<<1, 256, 0, stream>>>((const uint32*)x, flag);
    hipMemsetAsync(cnt, 0, (size_t)N * 4, stream);
    k_f1<<<197 + g256e4, 256, 0, stream>>>(
        d_in[3], d_in[7], d_in[11],
        d_in[4], d_in[8], d_in[12],
        d_in[5], d_in[9], d_in[13],
        d_in[6], d_in[10], d_in[14],
        pblk, flag, dst, cnt, rank, E);
    k_f2<<<nb + gg, 256, 0, stream>>>(cnt, ro, bsum, N, nb,
        x, pblk, hb, als, ald, pblk + 49152, pblk + 49536, N, flag);
    k_scan_bc<<<g256n, 256, 0, stream>>>(ro, bsum, N, nb);
    k_scatter<<<g256e4, 256, 0, stream>>>(src, dst, ro, rank, ssrc, E);

    int ga = (N + 1) / 2;
    for (int l = 0; l < 3; l++) {
        const ushort_t* As = pblk + 49152 + l * 128;
        const ushort_t* Ad = pblk + 49536 + l * 128;
        const ushort_t* Bc = pblk + 49920 + l * 128;
        void* outp = (l == 2) ? d_out : (void*)xact;
        if (l > 0) {
            const ushort_t* Wc = pblk + (size_t)l * 16384;
            k_gemm<<<gg, 256, 0, stream>>>(xact, Wc, hb, als, ald, As, Ad, N, flag);
        }
        k_agg<<<ga, 64, 0, stream>>>(ro, ssrc, hb, als, ald, Bc, outp, N, l < 2 ? 1 : 0,
                                     l == 2 ? 1 : 0, flag);
    }
}

// Round 10
// 335.132 us; speedup vs baseline: 1.0699x; 1.0057x over previous
//
#include <hip/hip_runtime.h>
#include <stdint.h>

typedef unsigned short ushort_t;
typedef unsigned int uint32;

typedef __attribute__((ext_vector_type(8))) short short8;
typedef __attribute__((ext_vector_type(4))) float floatx4;

#define NEG_SLOPE 0.2f

__device__ __forceinline__ ushort_t f2bf(float f) {
    union { float f; uint32 u; } v; v.f = f;
    uint32 u = v.u;
    uint32 r = (u + 0x7fffu + ((u >> 16) & 1u)) >> 16;
    return (ushort_t)r;
}
__device__ __forceinline__ float2 bf2x(uint32 u) {
    union { uint32 u; float f; } a, b;
    a.u = u << 16; b.u = u & 0xffff0000u;
    float2 r; r.x = a.f; r.y = b.f; return r;
}

// ---------------- dtype sniffer ----------------
__global__ void k_sniff(const uint32* __restrict__ x, int* __restrict__ flag) {
    __shared__ int sh[256];
    int t = threadIdx.x;
    int c = 0;
    for (int i = t; i < 1024; i += 256) {
        uint32 h = x[i] & 0xFFFFu;
        uint32 e = (h >> 7) & 0xFFu;
        if (h == 0u || (e >= 100u && e <= 140u)) c++;
    }
    sh[t] = c; __syncthreads();
    for (int off = 128; off >= 1; off >>= 1) {
        if (t < off) sh[t] += sh[t + off];
        __syncthreads();
    }
    if (t == 0) flag[0] = (sh[0] >= 512) ? 1 : 0;
}

// ---------------- GEMM body ----------------
__device__ __forceinline__ void gemm_body(int bid, int tid,
                                          const void* __restrict__ actv,
                                          const ushort_t* __restrict__ W,
                                          ushort_t* __restrict__ hb,
                                          float* __restrict__ als,
                                          float* __restrict__ ald,
                                          const ushort_t* __restrict__ asrcp,
                                          const ushort_t* __restrict__ adstp,
                                          int N, int layer0,
                                          const int* __restrict__ flag) {
    int wid = tid >> 6, lane = tid & 63;
    int n0 = (bid * 4 + wid) * 16;
    int mrow = lane & 15, quad = lane >> 4;
    int n = n0 + mrow;
    bool isf32 = (layer0 && !flag[0]);
    short8 a[4];
    if (n < N) {
        if (isf32) {
            const float* ar = (const float*)actv + (size_t)n * 128 + quad * 8;
            #pragma unroll
            for (int kt = 0; kt < 4; kt++) {
                float4 fa = *(const float4*)(ar + kt * 32);
                float4 fb = *(const float4*)(ar + kt * 32 + 4);
                short8 v;
                v[0] = (short)f2bf(fa.x); v[1] = (short)f2bf(fa.y);
                v[2] = (short)f2bf(fa.z); v[3] = (short)f2bf(fa.w);
                v[4] = (short)f2bf(fb.x); v[5] = (short)f2bf(fb.y);
                v[6] = (short)f2bf(fb.z); v[7] = (short)f2bf(fb.w);
                a[kt] = v;
            }
        } else {
            const ushort_t* ar = (const ushort_t*)actv + (size_t)n * 128 + quad * 8;
            #pragma unroll
            for (int kt = 0; kt < 4; kt++) a[kt] = *(const short8*)(ar + kt * 32);
        }
    } else {
        #pragma unroll
        for (int kt = 0; kt < 4; kt++) { short8 z = {0,0,0,0,0,0,0,0}; a[kt] = z; }
    }
    float ps[4], pd[4];
    #pragma unroll
    for (int t = 0; t < 8; t++) {
        if ((t & 1) == 0) {
            #pragma unroll
            for (int r = 0; r < 4; r++) { ps[r] = 0.f; pd[r] = 0.f; }
        }
        const ushort_t* wr = W + (size_t)(t * 16 + mrow) * 128 + quad * 8;
        floatx4 acc = {0.f, 0.f, 0.f, 0.f};
        #pragma unroll
        for (int kt = 0; kt < 4; kt++) {
            short8 b = *(const short8*)(wr + kt * 32);
            acc = __builtin_amdgcn_mfma_f32_16x16x32_bf16(a[kt], b, acc, 0, 0, 0);
        }
        int col = t * 16 + mrow;
        union { uint32 u; float f; } cs, cd;
        cs.u = ((uint32)asrcp[col]) << 16;
        cd.u = ((uint32)adstp[col]) << 16;
        #pragma unroll
        for (int r = 0; r < 4; r++) {
            int rn = n0 + quad * 4 + r;
            if (rn < N) hb[(size_t)rn * 128 + col] = f2bf(acc[r]);
            ps[r] += acc[r] * cs.f;
            pd[r] += acc[r] * cd.f;
        }
        if (t & 1) {
            #pragma unroll
            for (int off = 1; off <= 8; off <<= 1) {
                #pragma unroll
                for (int r = 0; r < 4; r++) {
                    ps[r] += __shfl_xor(ps[r], off);
                    pd[r] += __shfl_xor(pd[r], off);
                }
            }
            int h = t >> 1;
            if (mrow < 8) {
                int r = mrow & 3;
                float vs = r == 0 ? ps[0] : r == 1 ? ps[1] : r == 2 ? ps[2] : ps[3];
                float vd = r == 0 ? pd[0] : r == 1 ? pd[1] : r == 2 ? pd[2] : pd[3];
                int rn = n0 + quad * 4 + r;
                if (rn < N) {
                    float* dp = (mrow < 4) ? als : ald;
                    dp[(size_t)rn * 4 + h] = (mrow < 4) ? vs : vd;
                }
            }
        }
    }
}

__global__ __launch_bounds__(256) void k_gemm(const void* __restrict__ actv,
                                              const ushort_t* __restrict__ W,
                                              ushort_t* __restrict__ hb,
                                              float* __restrict__ als,
                                              float* __restrict__ ald,
                                              const ushort_t* __restrict__ asrcp,
                                              const ushort_t* __restrict__ adstp,
                                              int N, const int* __restrict__ flag) {
    gemm_body(blockIdx.x, threadIdx.x, actv, W, hb, als, ald, asrcp, adstp, N, 0, flag);
}

// ---------------- fused: param canonicalization (197 blocks) | hist x4-unrolled (rest) ----------------
__global__ void k_f1(const void* W0, const void* W1, const void* W2,
                     const void* s0, const void* s1, const void* s2,
                     const void* a0, const void* a1, const void* a2,
                     const void* b0, const void* b1, const void* b2,
                     ushort_t* __restrict__ pblk, const int* __restrict__ flag,
                     const int* __restrict__ dst, int* __restrict__ cnt,
                     int* __restrict__ rank, int E) {
    if (blockIdx.x < 197) {
        int i = blockIdx.x * 256 + threadIdx.x;
        if (i >= 50304) return;
        const void* src; int off;
        if (i < 49152) {
            int seg = i / 16384; off = i % 16384;
            src = seg == 0 ? W0 : seg == 1 ? W1 : W2;
        } else if (i < 49536) {
            int j = i - 49152; int seg = j / 128; off = j % 128;
            src = seg == 0 ? s0 : seg == 1 ? s1 : s2;
        } else if (i < 49920) {
            int j = i - 49536; int seg = j / 128; off = j % 128;
            src = seg == 0 ? a0 : seg == 1 ? a1 : a2;
        } else {
            int j = i - 49920; int seg = j / 128; off = j % 128;
            src = seg == 0 ? b0 : seg == 1 ? b1 : b2;
        }
        if (flag[0]) pblk[i] = ((const ushort_t*)src)[off];
        else         pblk[i] = f2bf(((const float*)src)[off]);
    } else {
        int e0 = ((blockIdx.x - 197) * 256 + threadIdx.x) * 4;
        if (e0 + 3 < E) {
            int4 d4 = *(const int4*)(dst + e0);
            int r0 = atomicAdd(&cnt[d4.x], 1);
            int r1 = atomicAdd(&cnt[d4.y], 1);
            int r2 = atomicAdd(&cnt[d4.z], 1);
            int r3 = atomicAdd(&cnt[d4.w], 1);
            int4 r4 = {r0, r1, r2, r3};
            *(int4*)(rank + e0) = r4;
        } else {
            for (int e = e0; e < E; e++) rank[e] = atomicAdd(&cnt[dst[e]], 1);
        }
    }
}

// ---------------- fused: scan_a (nb blocks) | gemm layer-0 (rest) ----------------
__global__ __launch_bounds__(256) void k_f2(const int* __restrict__ cnt, int* __restrict__ ro,
                                            int* __restrict__ bsum, int n, int nb,
                                            const void* __restrict__ actv,
                                            const ushort_t* __restrict__ W,
                                            ushort_t* __restrict__ hb,
                                            float* __restrict__ als, float* __restrict__ ald,
                                            const ushort_t* __restrict__ asrcp,
                                            const ushort_t* __restrict__ adstp,
                                            int N, const int* __restrict__ flag) {
    if ((int)blockIdx.x < nb) {
        __shared__ int sd[256];
        int t = threadIdx.x;
        int base = blockIdx.x * 1024 + t * 4;
        int v0 = (base + 0 < n) ? cnt[base + 0] : 0;
        int v1 = (base + 1 < n) ? cnt[base + 1] : 0;
        int v2 = (base + 2 < n) ? cnt[base + 2] : 0;
        int v3 = (base + 3 < n) ? cnt[base + 3] : 0;
        int s = v0 + v1 + v2 + v3;
        sd[t] = s; __syncthreads();
        for (int off = 1; off < 256; off <<= 1) {
            int x = 0;
            if (t >= off) x = sd[t - off];
            __syncthreads();
            sd[t] += x;
            __syncthreads();
        }
        int run = sd[t] - s;
        run += v0; if (base + 0 < n) ro[base + 1] = run;
        run += v1; if (base + 1 < n) ro[base + 2] = run;
        run += v2; if (base + 2 < n) ro[base + 3] = run;
        run += v3; if (base + 3 < n) ro[base + 4] = run;
        if (t == 255) bsum[blockIdx.x] = sd[255];
    } else {
        gemm_body(blockIdx.x - nb, threadIdx.x, actv, W, hb, als, ald, asrcp, adstp, N, 1, flag);
    }
}

__global__ void k_scan_bc(int* __restrict__ ro, const int* __restrict__ bsum,
                          int n, int nb) {
    __shared__ int pre[256];
    int t = threadIdx.x;
    if (t == 0) {
        int acc = 0;
        for (int b = 0; b < nb; b++) { pre[b] = acc; acc += bsum[b]; }
    }
    __syncthreads();
    int i = blockIdx.x * 256 + t;
    if (i == 0) ro[0] = 0;
    if (i < n) ro[i + 1] += pre[i >> 10];
}

// atomic-free scatter; u16 node indices (requires N < 65536); x4 unrolled
__global__ void k_scatter(const int* __restrict__ src, const int* __restrict__ dst,
                          const int* __restrict__ ro, const int* __restrict__ rank,
                          ushort_t* __restrict__ ssrc, int E) {
    int e0 = (blockIdx.x * 256 + threadIdx.x) * 4;
    if (e0 + 3 < E) {
        int4 d4 = *(const int4*)(dst + e0);
        int4 s4 = *(const int4*)(src + e0);
        int4 r4 = *(const int4*)(rank + e0);
        ssrc[ro[d4.x] + r4.x] = (ushort_t)s4.x;
        ssrc[ro[d4.y] + r4.y] = (ushort_t)s4.y;
        ssrc[ro[d4.z] + r4.z] = (ushort_t)s4.z;
        ssrc[ro[d4.w] + r4.w] = (ushort_t)s4.w;
    } else {
        for (int e = e0; e < E; e++) ssrc[ro[dst[e]] + rank[e]] = (ushort_t)src[e];
    }
}

// ---------------- softmax + aggregation: 1 wave / node, single pass, 2 edges/iter ----------------
// Gather loop: lanes 0-31 cover all 128 channels (4 ch/lane, uint2) of edge j,
// lanes 32-63 of edge j+1; shfl_xor(32) merges halves at the end.
__global__ __launch_bounds__(64) void k_agg(const int* __restrict__ ro,
                                            const ushort_t* __restrict__ ssrc,
                                            const ushort_t* __restrict__ hb,
                                            const float* __restrict__ als,
                                            const float* __restrict__ ald_,
                                            const ushort_t* __restrict__ bias,
                                            void* __restrict__ outp, int N, int apply_elu,
                                            int is_final, const int* __restrict__ flag) {
    int n = blockIdx.x;
    int lane = threadIdx.x;
    int r0 = ro[n], r1 = ro[n + 1];
    floatx4 ad = *(const floatx4*)(ald_ + (size_t)n * 4);
    const char* alsb = (const char*)als;

    __shared__ __align__(16) float wsm[260];
    __shared__ int osm[65];
    int eh = lane >> 5;                 // which edge of the pair
    int l5 = lane & 31;
    int hd = l5 >> 3;                   // head of my 4 channels
    int chb = l5 << 3;                  // byte offset of my 4 channels (8 B) within a 256 B row
    float a0 = 0.f, a1 = 0.f, a2 = 0.f, a3 = 0.f;
    float d0 = 0.f, d1 = 0.f, d2 = 0.f, d3 = 0.f;

    for (int base = r0; base < r1; base += 64) {
        int i = base + lane;
        int cend = min(64, r1 - base);
        if (i < r1) {
            int s = ssrc[i];
            floatx4 as = *(const floatx4*)(alsb + (s << 4));
            float t0 = as.x + ad.x; float w0 = __expf(fmaxf(t0, NEG_SLOPE * t0)); d0 += w0;
            float t1 = as.y + ad.y; float w1 = __expf(fmaxf(t1, NEG_SLOPE * t1)); d1 += w1;
            float t2 = as.z + ad.z; float w2 = __expf(fmaxf(t2, NEG_SLOPE * t2)); d2 += w2;
            float t3 = as.w + ad.w; float w3 = __expf(fmaxf(t3, NEG_SLOPE * t3)); d3 += w3;
            osm[lane] = s << 8;         // row byte offset
            floatx4 w4 = {w0, w1, w2, w3};
            *(floatx4*)(wsm + lane * 4) = w4;
        } else if (lane == cend) {      // zero-pad slot for the odd-tail trip
            osm[lane] = 0;
            floatx4 z = {0.f, 0.f, 0.f, 0.f};
            *(floatx4*)(wsm + lane * 4) = z;
        }
        __builtin_amdgcn_wave_barrier();
        int trips = (cend + 1) >> 1;    // 2 edges per trip (one per lane-half)
        #pragma unroll 2
        for (int j2 = 0; j2 < trips; j2++) {
            int e = j2 * 2 + eh;
            float wj = wsm[e * 4 + hd];
            uint2 h2 = *(const uint2*)((const char*)hb + (uint32)(osm[e] + chb));
            float2 p0 = bf2x(h2.x), p1 = bf2x(h2.y);
            a0 += wj * p0.x; a1 += wj * p0.y;
            a2 += wj * p1.x; a3 += wj * p1.y;
        }
        __builtin_amdgcn_wave_barrier();
    }
    // merge the two edge-halves (same channels, disjoint edges)
    a0 += __shfl_xor(a0, 32); a1 += __shfl_xor(a1, 32);
    a2 += __shfl_xor(a2, 32); a3 += __shfl_xor(a3, 32);
    // full-wave denominator reduce (each edge counted once across lanes)
    #pragma unroll
    for (int off = 32; off >= 1; off >>= 1) {
        d0 += __shfl_xor(d0, off); d1 += __shfl_xor(d1, off);
        d2 += __shfl_xor(d2, off); d3 += __shfl_xor(d3, off);
    }
    if (eh == 0) {
        float den = (hd == 0 ? d0 : hd == 1 ? d1 : hd == 2 ? d2 : d3) + 1e-16f;
        float inv = 1.0f / den;
        uint2 bb = *(const uint2*)((const char*)bias + chb);
        float2 bv0 = bf2x(bb.x), bv1 = bf2x(bb.y);
        float o0 = a0 * inv + bv0.x;
        float o1 = a1 * inv + bv0.y;
        float o2 = a2 * inv + bv1.x;
        float o3 = a3 * inv + bv1.y;
        if (apply_elu) {
            o0 = o0 > 0.f ? o0 : expm1f(o0);
            o1 = o1 > 0.f ? o1 : expm1f(o1);
            o2 = o2 > 0.f ? o2 : expm1f(o2);
            o3 = o3 > 0.f ? o3 : expm1f(o3);
        }
        if (is_final && !flag[0]) {
            float4 o4 = {o0, o1, o2, o3};
            *(float4*)((char*)outp + (size_t)n * 512 + chb * 2) = o4;
        } else {
            uint2 pk;
            pk.x = (uint32)f2bf(o0) | ((uint32)f2bf(o1) << 16);
            pk.y = (uint32)f2bf(o2) | ((uint32)f2bf(o3) << 16);
            *(uint2*)((char*)outp + (size_t)n * 256 + chb) = pk;
        }
    }
}

extern "C" void kernel_launch(void* const* d_in, const int* in_sizes, int n_in,
                              void* d_out, int out_size, void* d_ws, size_t ws_size,
                              hipStream_t stream) {
    const void* x = d_in[0];
    const int* src = (const int*)d_in[1];
    const int* dst = (const int*)d_in[2];
    const int N = in_sizes[0] / 128;   // 50000 (< 65536 required for u16 ssrc)
    const int E = in_sizes[1];

    char* p = (char*)d_ws;
    auto alloc = [&](size_t bytes) { char* r = p; p += (bytes + 255) & ~(size_t)255; return r; };
    int*      flag  = (int*)alloc(256);
    int*      bsum  = (int*)alloc(256 * 4);
    int*      ro    = (int*)alloc((size_t)(N + 1) * 4);
    ushort_t* ssrc  = (ushort_t*)alloc((size_t)E * 2);         // aliases cnt (int[N]) early
    ushort_t* hb    = (ushort_t*)alloc((size_t)N * 128 * 2);
    float*    als   = (float*)alloc((size_t)N * 4 * 4);
    float*    ald   = (float*)alloc((size_t)N * 4 * 4);
    ushort_t* xact  = (ushort_t*)alloc((size_t)N * 128 * 2);   // aliases rank (int[E]) early
    ushort_t* pblk  = (ushort_t*)alloc((size_t)50304 * 2);

    int* cnt  = (int*)ssrc;    // dead once scatter overwrites ssrc
    int* rank = (int*)xact;    // dead once agg0 writes xact

    int g256e4 = (E + 1023) / 1024;
    int g256n = (N + 255) / 256;
    int nb = (N + 1023) / 1024;
    int gg = (N + 63) / 64;

    k_sniff<<<1, 256, 0, stream>>>((const uint32*)x, flag);
    hipMemsetAsync(cnt, 0, (size_t)N * 4, stream);
    k_f1<<<197 + g256e4, 256, 0, stream>>>(
        d_in[3], d_in[7], d_in[11],
        d_in[4], d_in[8], d_in[12],
        d_in[5], d_in[9], d_in[13],
        d_in[6], d_in[10], d_in[14],
        pblk, flag, dst, cnt, rank, E);
    k_f2<<<nb + gg, 256, 0, stream>>>(cnt, ro, bsum, N, nb,
        x, pblk, hb, als, ald, pblk + 49152, pblk + 49536, N, flag);
    k_scan_bc<<<g256n, 256, 0, stream>>>(ro, bsum, N, nb);
    k_scatter<<<g256e4, 256, 0, stream>>>(src, dst, ro, rank, ssrc, E);

    for (int l = 0; l < 3; l++) {
        const ushort_t* As = pblk + 49152 + l * 128;
        const ushort_t* Ad = pblk + 49536 + l * 128;
        const ushort_t* Bc = pblk + 49920 + l * 128;
        void* outp = (l == 2) ? d_out : (void*)xact;
        if (l > 0) {
            const ushort_t* Wc = pblk + (size_t)l * 16384;
            k_gemm<<<gg, 256, 0, stream>>>(xact, Wc, hb, als, ald, As, Ad, N, flag);
        }
        k_agg<<<N, 64, 0, stream>>>(ro, ssrc, hb, als, ald, Bc, outp, N, l < 2 ? 1 : 0,
                                    l == 2 ? 1 : 0, flag);
    }
}